// Round 14
// baseline (61.281 us; speedup 1.0000x reference)
//
#include <hip/hip_runtime.h>
#include <hip/hip_fp16.h>

// Depthwise 3D Gaussian conv (1,3,160,160,160) fp32, K=25, radius=12.
// Separable -> three 1-D passes, fp16 intermediates (r11 structure).
// Round 14: conv_h/conv_d get a split-stage counted-vmcnt pipeline:
//   stage rows [0,64) -> raw barrier (NO vmcnt drain) -> compute hv=0
//   while rows [64,104) loads (issued pre-barrier into regs) are in
//   flight -> write them -> raw barrier -> compute hv=1.
// conv_w unchanged (r11). Fusion abandoned for good (5 attempts, 5 losses).

#define NV 160
constexpr int KS    = 25;
constexpr int RAD   = 12;
constexpr int PLANE = NV * NV;        // 25600
constexpr int VOL   = NV * NV * NV;   // 4,096,000
constexpr int TOT   = 3 * VOL;        // 12,288,000
constexpr int ROWS  = NV + 2 * RAD;   // 184

// W-pass geometry (r11/r9)
constexpr int PITCH = 17;             // float2 pitch
constexpr int OPT   = 10;
constexpr int WIN   = OPT + KS - 1;   // 34
constexpr int OROW  = 168;            // output-staging row pitch (halfs)

// H/D-pass geometry (full-w tiles)
constexpr int HC2   = 80;             // outputs per block along conv axis
constexpr int TR    = HC2 + 2 * RAD;  // 104 tile rows
constexpr int TP2   = 84;             // half2 pitch
constexpr int ATASK = 64 * 20;        // 1280 A-stage tasks (rows [0,64))
constexpr int BTASK = 40 * 20;        // 800  B-stage tasks (rows [64,104))

__device__ __forceinline__ void pk(float2& a, float2 g, float2 v) {
    asm("v_pk_fma_f32 %0, %1, %2, %0" : "+v"(a) : "v"(g), "v"(v));
}

// Recover g1[t] from k3: g1[t] = g3[t,12,12] / cbrt(g3[12,12,12])^2 (exact).
__device__ __forceinline__ void load_g(const float* __restrict__ k3, float* g) {
    float c   = k3[12 * 625 + 312];          // g1[12]^3
    float g12 = cbrtf(c);
    float inv = 1.0f / (g12 * g12);
#pragma unroll
    for (int t = 0; t < KS; ++t) g[t] = k3[t * 625 + 312] * inv;
}

// ---------------- W pass: f32 in -> f16 out (r11, proven) ----------------
__global__ __launch_bounds__(256) void conv_w(const float* __restrict__ in,
                                              __half* __restrict__ out,
                                              const float* __restrict__ k3) {
    __shared__ float2 T[ROWS][PITCH];        // 25024 B (reused as out-stage)
    float gs[KS];
    load_g(k3, gs);
    float2 g2[KS];
#pragma unroll
    for (int t = 0; t < KS; ++t) g2[t] = make_float2(gs[t], gs[t]);

    int tid = threadIdx.x;
    int b   = blockIdx.x;
    int ht  = b % 5;
    int cd  = b / 5;               // c*160 + d
    int h0  = ht * 32;
    const float* base = in + (size_t)cd * PLANE;

    int wl = tid & 31, hq = tid >> 5;        // wl 0..31, hq 0..7
#pragma unroll
    for (int hh = 0; hh < 2; ++hh) {
        int hp = hq + hh * 8;                // 0..15
        const float* r0 = base + (h0 + 2 * hp) * NV;
#pragma unroll
        for (int ib = 0; ib < ROWS; ib += 32) {
            int i = ib + wl;
            if (i < ROWS) {
                int wv = i - RAD;
                float a = 0.f, bb = 0.f;
                if (wv >= 0 && wv < NV) { a = r0[wv]; bb = r0[NV + wv]; }
                T[i][hp] = make_float2(a, bb);
            }
        }
    }
    __syncthreads();

    int p  = tid & 15;             // h-pair
    int ct = tid >> 4;             // 0..15
    int wb = ct * OPT;
    float2 acc[OPT];
#pragma unroll
    for (int j = 0; j < OPT; ++j) acc[j] = make_float2(0.f, 0.f);
#pragma unroll
    for (int it = 0; it < WIN; ++it) {
        float2 v = T[wb + it][p];
#pragma unroll
        for (int j = 0; j < OPT; ++j) {
            int t = it - j;
            if (t >= 0 && t < KS) pk(acc[j], g2[t], v);
        }
    }

    __syncthreads();
    __half* Ost = (__half*)(&T[0][0]);       // 32*336 = 10752 B <= 25024
#pragma unroll
    for (int j = 0; j < OPT; ++j) {
        Ost[(2 * p)     * OROW + wb + j] = __float2half_rn(acc[j].x);
        Ost[(2 * p + 1) * OROW + wb + j] = __float2half_rn(acc[j].y);
    }
    __syncthreads();
    __half* ob = out + (size_t)cd * PLANE + (size_t)h0 * NV;
#pragma unroll
    for (int it = 0; it < 3; ++it) {
        int task = it * 256 + tid;           // 640 = 32 rows x 20 chunks
        if (task < 640) {
            int chunk = task % 20, row = task / 20;
            uint4 v = *(const uint4*)(Ost + row * OROW + 8 * chunk);
            *(uint4*)(ob + (size_t)row * NV + 8 * chunk) = v;
        }
    }
}

// ---------------- H pass: f16 in -> f16 out (split-stage pipeline) ----------
__global__ __launch_bounds__(320) void conv_h(const __half* __restrict__ in,
                                              __half* __restrict__ out,
                                              const float* __restrict__ k3) {
    __shared__ __half2 T[TR][TP2];           // 104*84*4 = 34944 B
    float gs[KS];
    load_g(k3, gs);
    float2 g2[KS];
#pragma unroll
    for (int t = 0; t < KS; ++t) g2[t] = make_float2(gs[t], gs[t]);

    int tid = threadIdx.x;
    int b   = blockIdx.x;
    int hh  = b & 1;
    int cd  = b >> 1;              // c*160 + d
    int h0  = hh * HC2;
    const __half* base = in + (size_t)cd * PLANE;

    // ---- A stage: rows [0,64), reg-batched then written ----
    uint4 rA[4];
#pragma unroll
    for (int i = 0; i < 4; ++i) {
        int task = i * 320 + tid;            // < 1280, all valid
        int r = task / 20, k = task % 20;
        int hg = h0 - RAD + r;
        rA[i] = make_uint4(0u, 0u, 0u, 0u);
        if (hg >= 0 && hg < NV) rA[i] = *(const uint4*)(base + hg * NV + 8 * k);
    }
#pragma unroll
    for (int i = 0; i < 4; ++i) {
        int task = i * 320 + tid;
        int r = task / 20, k = task % 20;
        *(uint4*)(&T[r][4 * k]) = rA[i];
    }
    // ---- B loads issued (rows [64,104)), NOT consumed yet ----
    uint4 rB[3];
#pragma unroll
    for (int i = 0; i < 3; ++i) {
        int task = i * 320 + tid;            // < 800 valid
        rB[i] = make_uint4(0u, 0u, 0u, 0u);
        if (task < BTASK) {
            int r = 64 + task / 20, k = task % 20;
            int hg = h0 - RAD + r;
            if (hg >= 0 && hg < NV) rB[i] = *(const uint4*)(base + hg * NV + 8 * k);
        }
    }
    asm volatile("s_waitcnt lgkmcnt(0)" ::: "memory");
    __builtin_amdgcn_s_barrier();            // B loads stay in flight
    __builtin_amdgcn_sched_barrier(0);

    int wp = tid % 80, oc = tid / 80;        // wp 0..79, oc 0..3
    // ---- compute hv=0: rb in {0,10,20,30}, windows within rows [0,64) ----
    {
        int rb = oc * OPT;
        float2 acc[OPT];
#pragma unroll
        for (int j = 0; j < OPT; ++j) acc[j] = make_float2(0.f, 0.f);
#pragma unroll
        for (int it = 0; it < WIN; ++it) {
            float2 v = __half22float2(T[rb + it][wp]);
#pragma unroll
            for (int j = 0; j < OPT; ++j) {
                int t = it - j;
                if (t >= 0 && t < KS) pk(acc[j], g2[t], v);
            }
        }
        __half* op = out + (size_t)cd * PLANE + (size_t)(h0 + rb) * NV + 2 * wp;
#pragma unroll
        for (int j = 0; j < OPT; ++j)
            *(__half2*)(op + j * NV) = __float22half2_rn(acc[j]);
    }
    __builtin_amdgcn_sched_barrier(0);
    // ---- write B (compiler inserts counted vmcnt via data dependence) ----
#pragma unroll
    for (int i = 0; i < 3; ++i) {
        int task = i * 320 + tid;
        if (task < BTASK) {
            int r = 64 + task / 20, k = task % 20;
            *(uint4*)(&T[r][4 * k]) = rB[i];
        }
    }
    asm volatile("s_waitcnt lgkmcnt(0)" ::: "memory");
    __builtin_amdgcn_s_barrier();
    __builtin_amdgcn_sched_barrier(0);
    // ---- compute hv=1: rb in {40..70}, windows within rows [40,104) ----
    {
        int rb = (oc + 4) * OPT;
        float2 acc[OPT];
#pragma unroll
        for (int j = 0; j < OPT; ++j) acc[j] = make_float2(0.f, 0.f);
#pragma unroll
        for (int it = 0; it < WIN; ++it) {
            float2 v = __half22float2(T[rb + it][wp]);
#pragma unroll
            for (int j = 0; j < OPT; ++j) {
                int t = it - j;
                if (t >= 0 && t < KS) pk(acc[j], g2[t], v);
            }
        }
        __half* op = out + (size_t)cd * PLANE + (size_t)(h0 + rb) * NV + 2 * wp;
#pragma unroll
        for (int j = 0; j < OPT; ++j)
            *(__half2*)(op + j * NV) = __float22half2_rn(acc[j]);
    }
}

// ---------------- D pass: f16 in -> f32 out (split-stage pipeline) ----------
__global__ __launch_bounds__(320) void conv_d(const __half* __restrict__ in,
                                              float* __restrict__ out,
                                              const float* __restrict__ k3) {
    __shared__ __half2 T[TR][TP2];           // 34944 B
    float gs[KS];
    load_g(k3, gs);
    float2 g2[KS];
#pragma unroll
    for (int t = 0; t < KS; ++t) g2[t] = make_float2(gs[t], gs[t]);

    int tid = threadIdx.x;
    int b   = blockIdx.x;
    int dh  = b & 1;
    int ch  = b >> 1;              // c*160 + h
    int c   = ch / NV, h = ch % NV;
    int d0  = dh * HC2;
    const __half* base = in + (size_t)c * VOL + h * NV;

    uint4 rA[4];
#pragma unroll
    for (int i = 0; i < 4; ++i) {
        int task = i * 320 + tid;
        int r = task / 20, k = task % 20;
        int dg = d0 - RAD + r;
        rA[i] = make_uint4(0u, 0u, 0u, 0u);
        if (dg >= 0 && dg < NV)
            rA[i] = *(const uint4*)(base + (size_t)dg * PLANE + 8 * k);
    }
#pragma unroll
    for (int i = 0; i < 4; ++i) {
        int task = i * 320 + tid;
        int r = task / 20, k = task % 20;
        *(uint4*)(&T[r][4 * k]) = rA[i];
    }
    uint4 rB[3];
#pragma unroll
    for (int i = 0; i < 3; ++i) {
        int task = i * 320 + tid;
        rB[i] = make_uint4(0u, 0u, 0u, 0u);
        if (task < BTASK) {
            int r = 64 + task / 20, k = task % 20;
            int dg = d0 - RAD + r;
            if (dg >= 0 && dg < NV)
                rB[i] = *(const uint4*)(base + (size_t)dg * PLANE + 8 * k);
        }
    }
    asm volatile("s_waitcnt lgkmcnt(0)" ::: "memory");
    __builtin_amdgcn_s_barrier();
    __builtin_amdgcn_sched_barrier(0);

    int wp = tid % 80, oc = tid / 80;
    {
        int rb = oc * OPT;
        float2 acc[OPT];
#pragma unroll
        for (int j = 0; j < OPT; ++j) acc[j] = make_float2(0.f, 0.f);
#pragma unroll
        for (int it = 0; it < WIN; ++it) {
            float2 v = __half22float2(T[rb + it][wp]);
#pragma unroll
            for (int j = 0; j < OPT; ++j) {
                int t = it - j;
                if (t >= 0 && t < KS) pk(acc[j], g2[t], v);
            }
        }
        float* op = out + (size_t)c * VOL + h * NV + 2 * wp;
#pragma unroll
        for (int j = 0; j < OPT; ++j)
            *(float2*)(op + (size_t)(d0 + rb + j) * PLANE) = acc[j];
    }
    __builtin_amdgcn_sched_barrier(0);
#pragma unroll
    for (int i = 0; i < 3; ++i) {
        int task = i * 320 + tid;
        if (task < BTASK) {
            int r = 64 + task / 20, k = task % 20;
            *(uint4*)(&T[r][4 * k]) = rB[i];
        }
    }
    asm volatile("s_waitcnt lgkmcnt(0)" ::: "memory");
    __builtin_amdgcn_s_barrier();
    __builtin_amdgcn_sched_barrier(0);
    {
        int rb = (oc + 4) * OPT;
        float2 acc[OPT];
#pragma unroll
        for (int j = 0; j < OPT; ++j) acc[j] = make_float2(0.f, 0.f);
#pragma unroll
        for (int it = 0; it < WIN; ++it) {
            float2 v = __half22float2(T[rb + it][wp]);
#pragma unroll
            for (int j = 0; j < OPT; ++j) {
                int t = it - j;
                if (t >= 0 && t < KS) pk(acc[j], g2[t], v);
            }
        }
        float* op = out + (size_t)c * VOL + h * NV + 2 * wp;
#pragma unroll
        for (int j = 0; j < OPT; ++j)
            *(float2*)(op + (size_t)(d0 + rb + j) * PLANE) = acc[j];
    }
}

// Fallback (only if ws too small): direct 25^3-tap depthwise conv.
__global__ __launch_bounds__(256) void conv3d_direct(const float* __restrict__ x,
                                                     const float* __restrict__ k3,
                                                     float* __restrict__ out) {
    int idx = blockIdx.x * 256 + threadIdx.x;
    if (idx >= TOT) return;
    int w = idx % NV;
    int t = idx / NV;
    int h = t % NV; t /= NV;
    int d = t % NV;
    int c = t / NV;
    const float* kc = k3 + c * (KS * KS * KS);
    float acc = 0.f;
    for (int i = 0; i < KS; ++i) {
        int dd = d + i - RAD;
        if (dd < 0 || dd >= NV) continue;
        for (int j = 0; j < KS; ++j) {
            int hh = h + j - RAD;
            if (hh < 0 || hh >= NV) continue;
            const float* xr = x + (c * NV + dd) * NV * NV + hh * NV + (w - RAD);
            const float* kr = kc + (i * KS + j) * KS;
            int k0 = (RAD - w) > 0 ? (RAD - w) : 0;
            int k1 = (NV + RAD - w) < KS ? (NV + RAD - w) : KS;
            for (int k = k0; k < k1; ++k) acc += kr[k] * xr[k];
        }
    }
    out[idx] = acc;
}

extern "C" void kernel_launch(void* const* d_in, const int* in_sizes, int n_in,
                              void* d_out, int out_size, void* d_ws, size_t ws_size,
                              hipStream_t stream) {
    const float* x  = (const float*)d_in[0];
    const float* k3 = (const float*)d_in[1];
    float* out = (float*)d_out;

    if (ws_size >= (size_t)TOT * 2 * sizeof(__half)) {
        __half* tmpA = (__half*)d_ws;
        __half* tmpB = tmpA + TOT;
        conv_w<<<2400, 256, 0, stream>>>(x, tmpA, k3);        // f32 -> f16 (W)
        conv_h<<<480 * 2, 320, 0, stream>>>(tmpA, tmpB, k3);  // f16 -> f16 (H)
        conv_d<<<480 * 2, 320, 0, stream>>>(tmpB, out, k3);   // f16 -> f32 (D)
    } else {
        conv3d_direct<<<(TOT + 255) / 256, 256, 0, stream>>>(x, k3, out);
    }
}

// Round 15
// 56.167 us; speedup vs baseline: 1.0910x; 1.0910x over previous
//
#include <hip/hip_runtime.h>
#include <hip/hip_fp16.h>

// Depthwise 3D Gaussian conv (1,3,160,160,160) fp32, K=25, radius=12.
// Separable -> three 1-D passes, fp16 intermediates (r11 structure).
// Round 15: occupancy unlock.
//   - Gaussian weights moved to SGPRs (readfirstlane + "s" asm constraint
//     on v_pk_fma) + symmetric-13 -> frees ~50 VGPRs/thread.
//   - launch_bounds(...,8) pins VGPR <= 64 (waves/CU halve above 64, m69).
//   - conv_w: 512 thr, 25KB LDS -> 4 blocks/CU = 32 waves/CU.
//   - conv_h/d: 640 thr, 34.9KB -> 3 blocks/CU = 30 waves/CU.
//   - XCD-affinity swizzle: plane cd -> XCD cd%8 in conv_w AND conv_h so
//     the W->H handoff stays in the producing XCD's L2.

#define NV 160
constexpr int KS    = 25;
constexpr int RAD   = 12;
constexpr int PLANE = NV * NV;        // 25600
constexpr int VOL   = NV * NV * NV;   // 4,096,000
constexpr int TOT   = 3 * VOL;        // 12,288,000
constexpr int ROWS  = NV + 2 * RAD;   // 184

// W-pass geometry
constexpr int PITCH = 17;             // float2 pitch
constexpr int OPTW  = 5;              // outputs/thread (512 thr)
constexpr int WINW  = OPTW + KS - 1;  // 29
constexpr int OROW  = 168;            // output-staging row pitch (halfs)

// H/D-pass geometry (full-w tiles)
constexpr int HC2   = 80;             // outputs per block along conv axis
constexpr int TR    = HC2 + 2 * RAD;  // 104 tile rows
constexpr int TP2   = 84;             // half2 pitch
constexpr int NTASK = TR * 20;        // 2080 stage tasks (16B each)
constexpr int OPT   = 10;
constexpr int WIN   = OPT + KS - 1;   // 34

#define GW2(t) g2[(t) < 13 ? (t) : 24 - (t)]

// packed fma with SGPR-resident weight (src0 = SGPR pair, legal in VOP3P)
__device__ __forceinline__ void pks(float2& a, float2 g, float2 v) {
    asm("v_pk_fma_f32 %0, %1, %2, %0" : "+v"(a) : "s"(g), "v"(v));
}

__device__ __forceinline__ float uniformf(float x) {
    return __int_as_float(__builtin_amdgcn_readfirstlane(__float_as_int(x)));
}

// Recover unique half of g1 (g1[t]=g1[24-t]); force into SGPRs.
__device__ __forceinline__ void load_g13_sgpr(const float* __restrict__ k3,
                                              float2* g2) {
    float c   = k3[12 * 625 + 312];          // g1[12]^3
    float g12 = cbrtf(c);
    float inv = 1.0f / (g12 * g12);
#pragma unroll
    for (int t = 0; t < 13; ++t) {
        float u = uniformf(k3[t * 625 + 312] * inv);
        g2[t] = make_float2(u, u);
    }
}

// ---------------- W pass: f32 in -> f16 out (512 thr, 32 waves/CU) ----------
__global__ __launch_bounds__(512, 8) void conv_w(const float* __restrict__ in,
                                                 __half* __restrict__ out,
                                                 const float* __restrict__ k3) {
    __shared__ float2 T[ROWS][PITCH];        // 25024 B (reused as out-stage)
    float2 g2[13];
    load_g13_sgpr(k3, g2);

    int tid = threadIdx.x;
    int b   = blockIdx.x;
    // XCD-affinity: plane cd -> XCD cd%8 (grid 2400 = 8*300)
    int x8  = b & 7;
    int m   = b >> 3;              // 0..299
    int q   = m / 5;               // 0..59
    int ht  = m % 5;
    int cd  = 8 * q + x8;          // c*160 + d
    int h0  = ht * 32;
    const float* base = in + (size_t)cd * PLANE;

    // stage transposed: T[wi][hp] = {x[h0+2hp][wi-12], x[h0+2hp+1][wi-12]}
    int wl = tid & 31, hp = tid >> 5;        // wl 0..31, hp 0..15
    {
        const float* r0 = base + (h0 + 2 * hp) * NV;
#pragma unroll
        for (int ib = 0; ib < ROWS; ib += 32) {
            int i = ib + wl;
            if (i < ROWS) {
                int wv = i - RAD;
                float a = 0.f, bb = 0.f;
                if (wv >= 0 && wv < NV) { a = r0[wv]; bb = r0[NV + wv]; }
                T[i][hp] = make_float2(a, bb);
            }
        }
    }
    __syncthreads();

    int p  = tid & 15;             // h-pair
    int ct = tid >> 4;             // 0..31
    int wb = ct * OPTW;
    float2 acc[OPTW];
#pragma unroll
    for (int j = 0; j < OPTW; ++j) acc[j] = make_float2(0.f, 0.f);
#pragma unroll
    for (int it = 0; it < WINW; ++it) {
        float2 v = T[wb + it][p];
#pragma unroll
        for (int j = 0; j < OPTW; ++j) {
            int t = it - j;
            if (t >= 0 && t < KS) pks(acc[j], GW2(t), v);
        }
    }

    // coalesced store epilogue via LDS re-use
    __syncthreads();
    __half* Ost = (__half*)(&T[0][0]);       // 32*336 = 10752 B <= 25024
#pragma unroll
    for (int j = 0; j < OPTW; ++j) {
        Ost[(2 * p)     * OROW + wb + j] = __float2half_rn(acc[j].x);
        Ost[(2 * p + 1) * OROW + wb + j] = __float2half_rn(acc[j].y);
    }
    __syncthreads();
    __half* ob = out + (size_t)cd * PLANE + (size_t)h0 * NV;
#pragma unroll
    for (int it = 0; it < 2; ++it) {
        int task = it * 512 + tid;           // 640 = 32 rows x 20 chunks
        if (task < 640) {
            int chunk = task % 20, row = task / 20;
            uint4 v = *(const uint4*)(Ost + row * OROW + 8 * chunk);
            *(uint4*)(ob + (size_t)row * NV + 8 * chunk) = v;
        }
    }
}

// ---------------- H pass: f16 in -> f16 out (640 thr, 30 waves/CU) ----------
__global__ __launch_bounds__(640, 8) void conv_h(const __half* __restrict__ in,
                                                 __half* __restrict__ out,
                                                 const float* __restrict__ k3) {
    __shared__ __half2 T[TR][TP2];           // 104*84*4 = 34944 B
    float2 g2[13];
    load_g13_sgpr(k3, g2);

    int tid = threadIdx.x;
    int b   = blockIdx.x;
    // XCD-affinity: plane cd -> XCD cd%8 (grid 960 = 8*120), matches conv_w
    int x8  = b & 7;
    int m   = b >> 3;              // 0..119
    int q   = m >> 1;
    int hh  = m & 1;
    int cd  = 8 * q + x8;          // c*160 + d
    int h0  = hh * HC2;
    const __half* base = in + (size_t)cd * PLANE;

    // stage: linear 16B tasks over [104 rows][20 chunks] (rows contiguous)
#pragma unroll
    for (int it = 0; it < 4; ++it) {
        int task = it * 640 + tid;
        if (task < NTASK) {
            int r = task / 20, k = task % 20;
            int hg = h0 - RAD + r;
            uint4 v = make_uint4(0u, 0u, 0u, 0u);
            if (hg >= 0 && hg < NV)
                v = *(const uint4*)(base + hg * NV + 8 * k);
            *(uint4*)(&T[r][4 * k]) = v;
        }
    }
    __syncthreads();

    int wp = tid % 80, oc = tid / 80;        // wp 0..79, oc 0..7
    int rb = oc * OPT;                       // 0..70
    float2 acc[OPT];
#pragma unroll
    for (int j = 0; j < OPT; ++j) acc[j] = make_float2(0.f, 0.f);
#pragma unroll
    for (int it = 0; it < WIN; ++it) {
        float2 v = __half22float2(T[rb + it][wp]);
#pragma unroll
        for (int j = 0; j < OPT; ++j) {
            int t = it - j;
            if (t >= 0 && t < KS) pks(acc[j], GW2(t), v);
        }
    }
    __half* op = out + (size_t)cd * PLANE + (size_t)(h0 + rb) * NV + 2 * wp;
#pragma unroll
    for (int j = 0; j < OPT; ++j)
        *(__half2*)(op + j * NV) = __float22half2_rn(acc[j]);
}

// ---------------- D pass: f16 in -> f32 out (640 thr, 30 waves/CU) ----------
__global__ __launch_bounds__(640, 8) void conv_d(const __half* __restrict__ in,
                                                 float* __restrict__ out,
                                                 const float* __restrict__ k3) {
    __shared__ __half2 T[TR][TP2];           // 34944 B
    float2 g2[13];
    load_g13_sgpr(k3, g2);

    int tid = threadIdx.x;
    int b   = blockIdx.x;
    int dh  = b & 1;
    int ch  = b >> 1;              // c*160 + h
    int c   = ch / NV, h = ch % NV;
    int d0  = dh * HC2;
    const __half* base = in + (size_t)c * VOL + h * NV;

    // stage: [104 d-rows][20 chunks], 320B coalesced per row
#pragma unroll
    for (int it = 0; it < 4; ++it) {
        int task = it * 640 + tid;
        if (task < NTASK) {
            int r = task / 20, k = task % 20;
            int dg = d0 - RAD + r;
            uint4 v = make_uint4(0u, 0u, 0u, 0u);
            if (dg >= 0 && dg < NV)
                v = *(const uint4*)(base + (size_t)dg * PLANE + 8 * k);
            *(uint4*)(&T[r][4 * k]) = v;
        }
    }
    __syncthreads();

    int wp = tid % 80, oc = tid / 80;        // oc 0..7
    int rb = oc * OPT;                       // 0..70
    float2 acc[OPT];
#pragma unroll
    for (int j = 0; j < OPT; ++j) acc[j] = make_float2(0.f, 0.f);
#pragma unroll
    for (int it = 0; it < WIN; ++it) {
        float2 v = __half22float2(T[rb + it][wp]);
#pragma unroll
        for (int j = 0; j < OPT; ++j) {
            int t = it - j;
            if (t >= 0 && t < KS) pks(acc[j], GW2(t), v);
        }
    }
    float* op = out + (size_t)c * VOL + h * NV + 2 * wp;
#pragma unroll
    for (int j = 0; j < OPT; ++j)
        *(float2*)(op + (size_t)(d0 + rb + j) * PLANE) = acc[j];
}

// Fallback (only if ws too small): direct 25^3-tap depthwise conv.
__global__ __launch_bounds__(256) void conv3d_direct(const float* __restrict__ x,
                                                     const float* __restrict__ k3,
                                                     float* __restrict__ out) {
    int idx = blockIdx.x * 256 + threadIdx.x;
    if (idx >= TOT) return;
    int w = idx % NV;
    int t = idx / NV;
    int h = t % NV; t /= NV;
    int d = t % NV;
    int c = t / NV;
    const float* kc = k3 + c * (KS * KS * KS);
    float acc = 0.f;
    for (int i = 0; i < KS; ++i) {
        int dd = d + i - RAD;
        if (dd < 0 || dd >= NV) continue;
        for (int j = 0; j < KS; ++j) {
            int hh = h + j - RAD;
            if (hh < 0 || hh >= NV) continue;
            const float* xr = x + (c * NV + dd) * NV * NV + hh * NV + (w - RAD);
            const float* kr = kc + (i * KS + j) * KS;
            int k0 = (RAD - w) > 0 ? (RAD - w) : 0;
            int k1 = (NV + RAD - w) < KS ? (NV + RAD - w) : KS;
            for (int k = k0; k < k1; ++k) acc += kr[k] * xr[k];
        }
    }
    out[idx] = acc;
}

extern "C" void kernel_launch(void* const* d_in, const int* in_sizes, int n_in,
                              void* d_out, int out_size, void* d_ws, size_t ws_size,
                              hipStream_t stream) {
    const float* x  = (const float*)d_in[0];
    const float* k3 = (const float*)d_in[1];
    float* out = (float*)d_out;

    if (ws_size >= (size_t)TOT * 2 * sizeof(__half)) {
        __half* tmpA = (__half*)d_ws;
        __half* tmpB = tmpA + TOT;
        conv_w<<<2400, 512, 0, stream>>>(x, tmpA, k3);      // f32 -> f16 (W)
        conv_h<<<960, 640, 0, stream>>>(tmpA, tmpB, k3);    // f16 -> f16 (H)
        conv_d<<<960, 640, 0, stream>>>(tmpB, out, k3);     // f16 -> f32 (D)
    } else {
        conv3d_direct<<<(TOT + 255) / 256, 256, 0, stream>>>(x, k3, out);
    }
}

// Round 16
// 52.829 us; speedup vs baseline: 1.1600x; 1.0632x over previous
//
#include <hip/hip_runtime.h>
#include <hip/hip_fp16.h>

// Depthwise 3D Gaussian conv (1,3,160,160,160) fp32, K=25, radius=12.
// Separable -> three 1-D passes, fp16 intermediates (r11 structure).
// Round 16: conv_h/conv_d staging via __builtin_amdgcn_global_load_lds
// (16B direct-to-LDS, no VGPR round trip) + counted-vmcnt split barrier:
//   issue A-slots (rows<76) + B-slots -> vmcnt(2)+lgkm(0), raw barrier ->
//   compute hv=0 (B in flight) -> vmcnt(0), barrier -> compute hv=1.
// LDS tile unpadded (320 B/row, flat) so dest is linear as gll requires.
// conv_w unchanged (r11).

#define NV 160
constexpr int KS    = 25;
constexpr int RAD   = 12;
constexpr int PLANE = NV * NV;        // 25600
constexpr int VOL   = NV * NV * NV;   // 4,096,000
constexpr int TOT   = 3 * VOL;        // 12,288,000
constexpr int ROWS  = NV + 2 * RAD;   // 184

// W-pass geometry (r11/r9)
constexpr int PITCH = 17;             // float2 pitch
constexpr int OPT   = 10;
constexpr int WIN   = OPT + KS - 1;   // 34
constexpr int OROW  = 168;            // output-staging row pitch (halfs)

// H/D-pass geometry (full-w tiles, unpadded for gll)
constexpr int HC2    = 80;            // outputs per block along conv axis
constexpr int TR     = 104;           // tile rows (80 + 2*12)
constexpr int TPW    = 80;            // half2 per row (NO pad; 320 B/row)
constexpr int VROWS  = 92;            // valid (non-zero) rows per tile
constexpr int VSLOTS = VROWS * 20;    // 1840 16B slots
constexpr int ZSLOTS = 12 * 20;       // 240 16B zero slots

__device__ __forceinline__ void pk(float2& a, float2 g, float2 v) {
    asm("v_pk_fma_f32 %0, %1, %2, %0" : "+v"(a) : "v"(g), "v"(v));
}

// Recover g1[t] from k3: g1[t] = g3[t,12,12] / cbrt(g3[12,12,12])^2 (exact).
__device__ __forceinline__ void load_g(const float* __restrict__ k3, float* g) {
    float c   = k3[12 * 625 + 312];          // g1[12]^3
    float g12 = cbrtf(c);
    float inv = 1.0f / (g12 * g12);
#pragma unroll
    for (int t = 0; t < KS; ++t) g[t] = k3[t * 625 + 312] * inv;
}

__device__ __forceinline__ void gll16(const void* g, void* l) {
    __builtin_amdgcn_global_load_lds(
        (const __attribute__((address_space(1))) void*)g,
        (__attribute__((address_space(3))) void*)l, 16, 0, 0);
}

// ---------------- W pass: f32 in -> f16 out (r11, proven) ----------------
__global__ __launch_bounds__(256) void conv_w(const float* __restrict__ in,
                                              __half* __restrict__ out,
                                              const float* __restrict__ k3) {
    __shared__ float2 T[ROWS][PITCH];        // 25024 B (reused as out-stage)
    float gs[KS];
    load_g(k3, gs);
    float2 g2[KS];
#pragma unroll
    for (int t = 0; t < KS; ++t) g2[t] = make_float2(gs[t], gs[t]);

    int tid = threadIdx.x;
    int b   = blockIdx.x;
    int ht  = b % 5;
    int cd  = b / 5;               // c*160 + d
    int h0  = ht * 32;
    const float* base = in + (size_t)cd * PLANE;

    int wl = tid & 31, hq = tid >> 5;        // wl 0..31, hq 0..7
#pragma unroll
    for (int hh = 0; hh < 2; ++hh) {
        int hp = hq + hh * 8;                // 0..15
        const float* r0 = base + (h0 + 2 * hp) * NV;
#pragma unroll
        for (int ib = 0; ib < ROWS; ib += 32) {
            int i = ib + wl;
            if (i < ROWS) {
                int wv = i - RAD;
                float a = 0.f, bb = 0.f;
                if (wv >= 0 && wv < NV) { a = r0[wv]; bb = r0[NV + wv]; }
                T[i][hp] = make_float2(a, bb);
            }
        }
    }
    __syncthreads();

    int p  = tid & 15;             // h-pair
    int ct = tid >> 4;             // 0..15
    int wb = ct * OPT;
    float2 acc[OPT];
#pragma unroll
    for (int j = 0; j < OPT; ++j) acc[j] = make_float2(0.f, 0.f);
#pragma unroll
    for (int it = 0; it < WIN; ++it) {
        float2 v = T[wb + it][p];
#pragma unroll
        for (int j = 0; j < OPT; ++j) {
            int t = it - j;
            if (t >= 0 && t < KS) pk(acc[j], g2[t], v);
        }
    }

    __syncthreads();
    __half* Ost = (__half*)(&T[0][0]);       // 32*336 = 10752 B <= 25024
#pragma unroll
    for (int j = 0; j < OPT; ++j) {
        Ost[(2 * p)     * OROW + wb + j] = __float2half_rn(acc[j].x);
        Ost[(2 * p + 1) * OROW + wb + j] = __float2half_rn(acc[j].y);
    }
    __syncthreads();
    __half* ob = out + (size_t)cd * PLANE + (size_t)h0 * NV;
#pragma unroll
    for (int it = 0; it < 3; ++it) {
        int task = it * 256 + tid;           // 640 = 32 rows x 20 chunks
        if (task < 640) {
            int chunk = task % 20, row = task / 20;
            uint4 v = *(const uint4*)(Ost + row * OROW + 8 * chunk);
            *(uint4*)(ob + (size_t)row * NV + 8 * chunk) = v;
        }
    }
}

// ---------------- H pass: f16 in -> f16 out (gll + split barrier) ----------
__global__ __launch_bounds__(320) void conv_h(const __half* __restrict__ in,
                                              __half* __restrict__ out,
                                              const float* __restrict__ k3) {
    __shared__ __half2 T[TR][TPW];           // 104*320 = 33280 B, flat
    float gs[KS];
    load_g(k3, gs);
    float2 g2[KS];
#pragma unroll
    for (int t = 0; t < KS; ++t) g2[t] = make_float2(gs[t], gs[t]);

    int tid = threadIdx.x;
    int b   = blockIdx.x;
    int hh  = b & 1;
    int cd  = b >> 1;              // c*160 + d
    int h0  = hh * HC2;
    char* Tf = (char*)(&T[0][0]);

    // zero halo rows: hh=0 -> LDS rows [0,12); hh=1 -> rows [92,104)
    int zbase = (hh == 0) ? 0 : 92 * 320;
    if (tid < ZSLOTS)
        *(uint4*)(Tf + zbase + tid * 16) = make_uint4(0u, 0u, 0u, 0u);

    // gll valid span: hh=0 -> LDS rows [12,104) <- h 0..91 (contiguous!)
    //                 hh=1 -> LDS rows [0,92)  <- h 68..159
    int vbase = (hh == 0) ? 12 * 320 : 0;
    const char* gsrc = (const char*)(in + (size_t)cd * PLANE
                                     + (size_t)((hh == 0) ? 0 : 68) * NV);
    int wavebase = tid & ~63;
    // A: iterations 0..3 (slots < 1280, LDS rows < 76+vrow0) ; B: rest
#pragma unroll
    for (int it = 0; it < 4; ++it) {
        int sw = it * 320 + wavebase;
        gll16(gsrc + (size_t)(sw + (tid & 63)) * 16, Tf + vbase + sw * 16);
    }
#pragma unroll
    for (int it = 4; it < 6; ++it) {
        int slot = it * 320 + tid;
        if (slot < VSLOTS) {
            int sw = it * 320 + wavebase;
            gll16(gsrc + (size_t)slot * 16, Tf + vbase + sw * 16);
        }
    }
    asm volatile("s_waitcnt vmcnt(2) lgkmcnt(0)" ::: "memory");
    __builtin_amdgcn_s_barrier();
    __builtin_amdgcn_sched_barrier(0);

    int wp = tid % 80, oc = tid / 80;        // wp 0..79, oc 0..3
    // ---- compute hv=0: rb in {0,10,20,30}, reads rows [0,64) ----
    {
        int rb = oc * OPT;
        float2 acc[OPT];
#pragma unroll
        for (int j = 0; j < OPT; ++j) acc[j] = make_float2(0.f, 0.f);
#pragma unroll
        for (int it = 0; it < WIN; ++it) {
            float2 v = __half22float2(T[rb + it][wp]);
#pragma unroll
            for (int j = 0; j < OPT; ++j) {
                int t = it - j;
                if (t >= 0 && t < KS) pk(acc[j], g2[t], v);
            }
        }
        __half* op = out + (size_t)cd * PLANE + (size_t)(h0 + rb) * NV + 2 * wp;
#pragma unroll
        for (int j = 0; j < OPT; ++j)
            *(__half2*)(op + j * NV) = __float22half2_rn(acc[j]);
    }
    __builtin_amdgcn_sched_barrier(0);
    asm volatile("s_waitcnt vmcnt(0)" ::: "memory");
    __builtin_amdgcn_s_barrier();
    __builtin_amdgcn_sched_barrier(0);
    // ---- compute hv=1: rb in {40..70}, reads rows [40,104) ----
    {
        int rb = (oc + 4) * OPT;
        float2 acc[OPT];
#pragma unroll
        for (int j = 0; j < OPT; ++j) acc[j] = make_float2(0.f, 0.f);
#pragma unroll
        for (int it = 0; it < WIN; ++it) {
            float2 v = __half22float2(T[rb + it][wp]);
#pragma unroll
            for (int j = 0; j < OPT; ++j) {
                int t = it - j;
                if (t >= 0 && t < KS) pk(acc[j], g2[t], v);
            }
        }
        __half* op = out + (size_t)cd * PLANE + (size_t)(h0 + rb) * NV + 2 * wp;
#pragma unroll
        for (int j = 0; j < OPT; ++j)
            *(__half2*)(op + j * NV) = __float22half2_rn(acc[j]);
    }
}

// ---------------- D pass: f16 in -> f32 out (gll + split barrier) ----------
__global__ __launch_bounds__(320) void conv_d(const __half* __restrict__ in,
                                              float* __restrict__ out,
                                              const float* __restrict__ k3) {
    __shared__ __half2 T[TR][TPW];           // 33280 B, flat
    float gs[KS];
    load_g(k3, gs);
    float2 g2[KS];
#pragma unroll
    for (int t = 0; t < KS; ++t) g2[t] = make_float2(gs[t], gs[t]);

    int tid = threadIdx.x;
    int b   = blockIdx.x;
    int dh  = b & 1;
    int ch  = b >> 1;              // c*160 + h
    int c   = ch / NV, h = ch % NV;
    int d0  = dh * HC2;
    char* Tf = (char*)(&T[0][0]);

    int zbase = (dh == 0) ? 0 : 92 * 320;
    if (tid < ZSLOTS)
        *(uint4*)(Tf + zbase + tid * 16) = make_uint4(0u, 0u, 0u, 0u);

    int vbase = (dh == 0) ? 12 * 320 : 0;
    int dg0   = (dh == 0) ? 0 : 68;
    const char* gd = (const char*)(in + (size_t)c * VOL + h * NV
                                   + (size_t)dg0 * PLANE);
    int wavebase = tid & ~63;
#pragma unroll
    for (int it = 0; it < 4; ++it) {
        int slot = it * 320 + tid;
        int rr = slot / 20, cc = slot % 20;
        int sw = it * 320 + wavebase;
        gll16(gd + (size_t)rr * (PLANE * 2) + cc * 16, Tf + vbase + sw * 16);
    }
#pragma unroll
    for (int it = 4; it < 6; ++it) {
        int slot = it * 320 + tid;
        if (slot < VSLOTS) {
            int rr = slot / 20, cc = slot % 20;
            int sw = it * 320 + wavebase;
            gll16(gd + (size_t)rr * (PLANE * 2) + cc * 16, Tf + vbase + sw * 16);
        }
    }
    asm volatile("s_waitcnt vmcnt(2) lgkmcnt(0)" ::: "memory");
    __builtin_amdgcn_s_barrier();
    __builtin_amdgcn_sched_barrier(0);

    int wp = tid % 80, oc = tid / 80;
    {
        int rb = oc * OPT;
        float2 acc[OPT];
#pragma unroll
        for (int j = 0; j < OPT; ++j) acc[j] = make_float2(0.f, 0.f);
#pragma unroll
        for (int it = 0; it < WIN; ++it) {
            float2 v = __half22float2(T[rb + it][wp]);
#pragma unroll
            for (int j = 0; j < OPT; ++j) {
                int t = it - j;
                if (t >= 0 && t < KS) pk(acc[j], g2[t], v);
            }
        }
        float* op = out + (size_t)c * VOL + h * NV + 2 * wp;
#pragma unroll
        for (int j = 0; j < OPT; ++j)
            *(float2*)(op + (size_t)(d0 + rb + j) * PLANE) = acc[j];
    }
    __builtin_amdgcn_sched_barrier(0);
    asm volatile("s_waitcnt vmcnt(0)" ::: "memory");
    __builtin_amdgcn_s_barrier();
    __builtin_amdgcn_sched_barrier(0);
    {
        int rb = (oc + 4) * OPT;
        float2 acc[OPT];
#pragma unroll
        for (int j = 0; j < OPT; ++j) acc[j] = make_float2(0.f, 0.f);
#pragma unroll
        for (int it = 0; it < WIN; ++it) {
            float2 v = __half22float2(T[rb + it][wp]);
#pragma unroll
            for (int j = 0; j < OPT; ++j) {
                int t = it - j;
                if (t >= 0 && t < KS) pk(acc[j], g2[t], v);
            }
        }
        float* op = out + (size_t)c * VOL + h * NV + 2 * wp;
#pragma unroll
        for (int j = 0; j < OPT; ++j)
            *(float2*)(op + (size_t)(d0 + rb + j) * PLANE) = acc[j];
    }
}

// Fallback (only if ws too small): direct 25^3-tap depthwise conv.
__global__ __launch_bounds__(256) void conv3d_direct(const float* __restrict__ x,
                                                     const float* __restrict__ k3,
                                                     float* __restrict__ out) {
    int idx = blockIdx.x * 256 + threadIdx.x;
    if (idx >= TOT) return;
    int w = idx % NV;
    int t = idx / NV;
    int h = t % NV; t /= NV;
    int d = t % NV;
    int c = t / NV;
    const float* kc = k3 + c * (KS * KS * KS);
    float acc = 0.f;
    for (int i = 0; i < KS; ++i) {
        int dd = d + i - RAD;
        if (dd < 0 || dd >= NV) continue;
        for (int j = 0; j < KS; ++j) {
            int hh = h + j - RAD;
            if (hh < 0 || hh >= NV) continue;
            const float* xr = x + (c * NV + dd) * NV * NV + hh * NV + (w - RAD);
            const float* kr = kc + (i * KS + j) * KS;
            int k0 = (RAD - w) > 0 ? (RAD - w) : 0;
            int k1 = (NV + RAD - w) < KS ? (NV + RAD - w) : KS;
            for (int k = k0; k < k1; ++k) acc += kr[k] * xr[k];
        }
    }
    out[idx] = acc;
}

extern "C" void kernel_launch(void* const* d_in, const int* in_sizes, int n_in,
                              void* d_out, int out_size, void* d_ws, size_t ws_size,
                              hipStream_t stream) {
    const float* x  = (const float*)d_in[0];
    const float* k3 = (const float*)d_in[1];
    float* out = (float*)d_out;

    if (ws_size >= (size_t)TOT * 2 * sizeof(__half)) {
        __half* tmpA = (__half*)d_ws;
        __half* tmpB = tmpA + TOT;
        conv_w<<<2400, 256, 0, stream>>>(x, tmpA, k3);        // f32 -> f16 (W)
        conv_h<<<480 * 2, 320, 0, stream>>>(tmpA, tmpB, k3);  // f16 -> f16 (H)
        conv_d<<<480 * 2, 320, 0, stream>>>(tmpB, out, k3);   // f16 -> f32 (D)
    } else {
        conv3d_direct<<<(TOT + 255) / 256, 256, 0, stream>>>(x, k3, out);
    }
}

// Round 18
// 51.899 us; speedup vs baseline: 1.1808x; 1.0179x over previous
//
#include <hip/hip_runtime.h>
#include <hip/hip_fp16.h>

// Depthwise 3D Gaussian conv (1,3,160,160,160) fp32, K=25, radius=12.
// Separable -> three 1-D passes, fp16 intermediates.
// Round 18: r16 base (proven, replay-validated) + conv_w rebuilt with
// gll row-major staging and a PLAIN __syncthreads (full drain, m97
// pattern) -- r17's split-vmcnt conv_w raced under graph replay and is
// reverted. conv_h / conv_d verbatim r16 (gll + counted split barrier,
// replay-proven).

#define NV 160
constexpr int KS    = 25;
constexpr int RAD   = 12;
constexpr int PLANE = NV * NV;        // 25600
constexpr int VOL   = NV * NV * NV;   // 4,096,000
constexpr int TOT   = 3 * VOL;        // 12,288,000

// W-pass geometry (row-major gll)
constexpr int WR    = 32;             // h rows per block
constexpr int OPT   = 10;
constexpr int WIN   = OPT + KS - 1;   // 34

// H/D-pass geometry (full-w tiles, unpadded for gll)
constexpr int HC2    = 80;            // outputs per block along conv axis
constexpr int TR     = 104;           // tile rows (80 + 2*12)
constexpr int TPW    = 80;            // half2 per row (NO pad; 320 B/row)
constexpr int VROWS  = 92;            // valid (non-zero) rows per tile
constexpr int VSLOTS = VROWS * 20;    // 1840 16B slots
constexpr int ZSLOTS = 12 * 20;       // 240 16B zero slots

#define GWS(t) gs[(t) < 13 ? (t) : 24 - (t)]

__device__ __forceinline__ void pk(float2& a, float2 g, float2 v) {
    asm("v_pk_fma_f32 %0, %1, %2, %0" : "+v"(a) : "v"(g), "v"(v));
}

// Recover g1[t] from k3: g1[t] = g3[t,12,12] / cbrt(g3[12,12,12])^2 (exact).
__device__ __forceinline__ void load_g(const float* __restrict__ k3, float* g) {
    float c   = k3[12 * 625 + 312];          // g1[12]^3
    float g12 = cbrtf(c);
    float inv = 1.0f / (g12 * g12);
#pragma unroll
    for (int t = 0; t < KS; ++t) g[t] = k3[t * 625 + 312] * inv;
}

// symmetric half only (13 values)
__device__ __forceinline__ void load_g13(const float* __restrict__ k3, float* g) {
    float c   = k3[12 * 625 + 312];
    float g12 = cbrtf(c);
    float inv = 1.0f / (g12 * g12);
#pragma unroll
    for (int t = 0; t < 13; ++t) g[t] = k3[t * 625 + 312] * inv;
}

__device__ __forceinline__ void gll16(const void* g, void* l) {
    __builtin_amdgcn_global_load_lds(
        (const __attribute__((address_space(1))) void*)g,
        (__attribute__((address_space(3))) void*)l, 16, 0, 0);
}

// ---------------- W pass: f32 in -> f16 out (gll row-major, full drain) ----
__global__ __launch_bounds__(256) void conv_w(const float* __restrict__ in,
                                              __half* __restrict__ out,
                                              const float* __restrict__ k3) {
    __shared__ float X[WR][NV];              // 32*640 = 20480 B, flat
    float gs[13];
    load_g13(k3, gs);

    int tid = threadIdx.x;
    int b   = blockIdx.x;
    int hc  = b % 5;
    int cd  = b / 5;               // c*160 + d
    int h0  = hc * WR;
    const char* gsrc = (const char*)(in + (size_t)cd * PLANE + (size_t)h0 * NV);
    char* Xf = (char*)(&X[0][0]);
    int wavebase = tid & ~63;

    // 1280 slots of 16B; source span fully contiguous (20.5 KB)
#pragma unroll
    for (int it = 0; it < 5; ++it) {
        int sw = it * 256 + wavebase;
        gll16(gsrc + (size_t)(sw + (tid & 63)) * 16, Xf + sw * 16);
    }
    __syncthreads();                         // full drain: proven-safe

    int c  = tid & 15;             // w-chunk
    int rr = tid >> 4;             // 0..15

#pragma unroll
    for (int ph = 0; ph < 2; ++ph) {
        int row = rr + 16 * ph;
        float acc[OPT];
#pragma unroll
        for (int j = 0; j < OPT; ++j) acc[j] = 0.f;
#pragma unroll
        for (int it = 0; it < WIN; ++it) {
            int wq = c * OPT + it - RAD;         // -12..171
            int wc = min(max(wq, 0), NV - 1);
            float v = X[row][wc];
            v = (wq == wc) ? v : 0.f;
#pragma unroll
            for (int j = 0; j < OPT; ++j) {
                int t = it - j;
                if (t >= 0 && t < KS) acc[j] = fmaf(GWS(t), v, acc[j]);
            }
        }
        __half* ob = out + (size_t)cd * PLANE + (size_t)(h0 + row) * NV + c * OPT;
#pragma unroll
        for (int j = 0; j < OPT / 2; ++j)
            *(__half2*)(ob + 2 * j) =
                __float22half2_rn(make_float2(acc[2 * j], acc[2 * j + 1]));
    }
}

// ---------------- H pass: f16 in -> f16 out (r16, gll + split) ----------
__global__ __launch_bounds__(320) void conv_h(const __half* __restrict__ in,
                                              __half* __restrict__ out,
                                              const float* __restrict__ k3) {
    __shared__ __half2 T[TR][TPW];           // 104*320 = 33280 B, flat
    float gsv[KS];
    load_g(k3, gsv);
    float2 g2[KS];
#pragma unroll
    for (int t = 0; t < KS; ++t) g2[t] = make_float2(gsv[t], gsv[t]);

    int tid = threadIdx.x;
    int b   = blockIdx.x;
    int hh  = b & 1;
    int cd  = b >> 1;              // c*160 + d
    int h0  = hh * HC2;
    char* Tf = (char*)(&T[0][0]);

    int zbase = (hh == 0) ? 0 : 92 * 320;
    if (tid < ZSLOTS)
        *(uint4*)(Tf + zbase + tid * 16) = make_uint4(0u, 0u, 0u, 0u);

    int vbase = (hh == 0) ? 12 * 320 : 0;
    const char* gsrc = (const char*)(in + (size_t)cd * PLANE
                                     + (size_t)((hh == 0) ? 0 : 68) * NV);
    int wavebase = tid & ~63;
#pragma unroll
    for (int it = 0; it < 4; ++it) {
        int sw = it * 320 + wavebase;
        gll16(gsrc + (size_t)(sw + (tid & 63)) * 16, Tf + vbase + sw * 16);
    }
#pragma unroll
    for (int it = 4; it < 6; ++it) {
        int slot = it * 320 + tid;
        if (slot < VSLOTS) {
            int sw = it * 320 + wavebase;
            gll16(gsrc + (size_t)slot * 16, Tf + vbase + sw * 16);
        }
    }
    asm volatile("s_waitcnt vmcnt(2) lgkmcnt(0)" ::: "memory");
    __builtin_amdgcn_s_barrier();
    __builtin_amdgcn_sched_barrier(0);

    int wp = tid % 80, oc = tid / 80;        // wp 0..79, oc 0..3
    {
        int rb = oc * OPT;
        float2 acc[OPT];
#pragma unroll
        for (int j = 0; j < OPT; ++j) acc[j] = make_float2(0.f, 0.f);
#pragma unroll
        for (int it = 0; it < WIN; ++it) {
            float2 v = __half22float2(T[rb + it][wp]);
#pragma unroll
            for (int j = 0; j < OPT; ++j) {
                int t = it - j;
                if (t >= 0 && t < KS) pk(acc[j], g2[t], v);
            }
        }
        __half* op = out + (size_t)cd * PLANE + (size_t)(h0 + rb) * NV + 2 * wp;
#pragma unroll
        for (int j = 0; j < OPT; ++j)
            *(__half2*)(op + j * NV) = __float22half2_rn(acc[j]);
    }
    __builtin_amdgcn_sched_barrier(0);
    asm volatile("s_waitcnt vmcnt(0)" ::: "memory");
    __builtin_amdgcn_s_barrier();
    __builtin_amdgcn_sched_barrier(0);
    {
        int rb = (oc + 4) * OPT;
        float2 acc[OPT];
#pragma unroll
        for (int j = 0; j < OPT; ++j) acc[j] = make_float2(0.f, 0.f);
#pragma unroll
        for (int it = 0; it < WIN; ++it) {
            float2 v = __half22float2(T[rb + it][wp]);
#pragma unroll
            for (int j = 0; j < OPT; ++j) {
                int t = it - j;
                if (t >= 0 && t < KS) pk(acc[j], g2[t], v);
            }
        }
        __half* op = out + (size_t)cd * PLANE + (size_t)(h0 + rb) * NV + 2 * wp;
#pragma unroll
        for (int j = 0; j < OPT; ++j)
            *(__half2*)(op + j * NV) = __float22half2_rn(acc[j]);
    }
}

// ---------------- D pass: f16 in -> f32 out (r16, gll + split) ----------
__global__ __launch_bounds__(320) void conv_d(const __half* __restrict__ in,
                                              float* __restrict__ out,
                                              const float* __restrict__ k3) {
    __shared__ __half2 T[TR][TPW];           // 33280 B, flat
    float gsv[KS];
    load_g(k3, gsv);
    float2 g2[KS];
#pragma unroll
    for (int t = 0; t < KS; ++t) g2[t] = make_float2(gsv[t], gsv[t]);

    int tid = threadIdx.x;
    int b   = blockIdx.x;
    int dh  = b & 1;
    int ch  = b >> 1;              // c*160 + h
    int c   = ch / NV, h = ch % NV;
    int d0  = dh * HC2;
    char* Tf = (char*)(&T[0][0]);

    int zbase = (dh == 0) ? 0 : 92 * 320;
    if (tid < ZSLOTS)
        *(uint4*)(Tf + zbase + tid * 16) = make_uint4(0u, 0u, 0u, 0u);

    int vbase = (dh == 0) ? 12 * 320 : 0;
    int dg0   = (dh == 0) ? 0 : 68;
    const char* gd = (const char*)(in + (size_t)c * VOL + h * NV
                                   + (size_t)dg0 * PLANE);
    int wavebase = tid & ~63;
#pragma unroll
    for (int it = 0; it < 4; ++it) {
        int slot = it * 320 + tid;
        int rr = slot / 20, cc = slot % 20;
        int sw = it * 320 + wavebase;
        gll16(gd + (size_t)rr * (PLANE * 2) + cc * 16, Tf + vbase + sw * 16);
    }
#pragma unroll
    for (int it = 4; it < 6; ++it) {
        int slot = it * 320 + tid;
        if (slot < VSLOTS) {
            int rr = slot / 20, cc = slot % 20;
            int sw = it * 320 + wavebase;
            gll16(gd + (size_t)rr * (PLANE * 2) + cc * 16, Tf + vbase + sw * 16);
        }
    }
    asm volatile("s_waitcnt vmcnt(2) lgkmcnt(0)" ::: "memory");
    __builtin_amdgcn_s_barrier();
    __builtin_amdgcn_sched_barrier(0);

    int wp = tid % 80, oc = tid / 80;
    {
        int rb = oc * OPT;
        float2 acc[OPT];
#pragma unroll
        for (int j = 0; j < OPT; ++j) acc[j] = make_float2(0.f, 0.f);
#pragma unroll
        for (int it = 0; it < WIN; ++it) {
            float2 v = __half22float2(T[rb + it][wp]);
#pragma unroll
            for (int j = 0; j < OPT; ++j) {
                int t = it - j;
                if (t >= 0 && t < KS) pk(acc[j], g2[t], v);
            }
        }
        float* op = out + (size_t)c * VOL + h * NV + 2 * wp;
#pragma unroll
        for (int j = 0; j < OPT; ++j)
            *(float2*)(op + (size_t)(d0 + rb + j) * PLANE) = acc[j];
    }
    __builtin_amdgcn_sched_barrier(0);
    asm volatile("s_waitcnt vmcnt(0)" ::: "memory");
    __builtin_amdgcn_s_barrier();
    __builtin_amdgcn_sched_barrier(0);
    {
        int rb = (oc + 4) * OPT;
        float2 acc[OPT];
#pragma unroll
        for (int j = 0; j < OPT; ++j) acc[j] = make_float2(0.f, 0.f);
#pragma unroll
        for (int it = 0; it < WIN; ++it) {
            float2 v = __half22float2(T[rb + it][wp]);
#pragma unroll
            for (int j = 0; j < OPT; ++j) {
                int t = it - j;
                if (t >= 0 && t < KS) pk(acc[j], g2[t], v);
            }
        }
        float* op = out + (size_t)c * VOL + h * NV + 2 * wp;
#pragma unroll
        for (int j = 0; j < OPT; ++j)
            *(float2*)(op + (size_t)(d0 + rb + j) * PLANE) = acc[j];
    }
}

// Fallback (only if ws too small): direct 25^3-tap depthwise conv.
__global__ __launch_bounds__(256) void conv3d_direct(const float* __restrict__ x,
                                                     const float* __restrict__ k3,
                                                     float* __restrict__ out) {
    int idx = blockIdx.x * 256 + threadIdx.x;
    if (idx >= TOT) return;
    int w = idx % NV;
    int t = idx / NV;
    int h = t % NV; t /= NV;
    int d = t % NV;
    int c = t / NV;
    const float* kc = k3 + c * (KS * KS * KS);
    float acc = 0.f;
    for (int i = 0; i < KS; ++i) {
        int dd = d + i - RAD;
        if (dd < 0 || dd >= NV) continue;
        for (int j = 0; j < KS; ++j) {
            int hh = h + j - RAD;
            if (hh < 0 || hh >= NV) continue;
            const float* xr = x + (c * NV + dd) * NV * NV + hh * NV + (w - RAD);
            const float* kr = kc + (i * KS + j) * KS;
            int k0 = (RAD - w) > 0 ? (RAD - w) : 0;
            int k1 = (NV + RAD - w) < KS ? (NV + RAD - w) : KS;
            for (int k = k0; k < k1; ++k) acc += kr[k] * xr[k];
        }
    }
    out[idx] = acc;
}

extern "C" void kernel_launch(void* const* d_in, const int* in_sizes, int n_in,
                              void* d_out, int out_size, void* d_ws, size_t ws_size,
                              hipStream_t stream) {
    const float* x  = (const float*)d_in[0];
    const float* k3 = (const float*)d_in[1];
    float* out = (float*)d_out;

    if (ws_size >= (size_t)TOT * 2 * sizeof(__half)) {
        __half* tmpA = (__half*)d_ws;
        __half* tmpB = tmpA + TOT;
        conv_w<<<480 * 5, 256, 0, stream>>>(x, tmpA, k3);     // f32 -> f16 (W)
        conv_h<<<480 * 2, 320, 0, stream>>>(tmpA, tmpB, k3);  // f16 -> f16 (H)
        conv_d<<<480 * 2, 320, 0, stream>>>(tmpB, out, k3);   // f16 -> f32 (D)
    } else {
        conv3d_direct<<<(TOT + 255) / 256, 256, 0, stream>>>(x, k3, out);
    }
}